// Round 1
// baseline (50.697 us; speedup 1.0000x reference)
//
#include <hip/hip_runtime.h>

// Problem shape (fixed by reference):
//   logits: [E=4, B=8192, C=1000] f32
//   target: [B] int
//   out:    [E] f32
constexpr int E_  = 4;
constexpr int B_  = 8192;
constexpr int C_  = 1000;
constexpr int CQ_ = C_ / 4;   // 250 float4 column-quads
constexpr int NB_ = 64;       // batch rows per block
constexpr int NCHUNK_ = B_ / NB_;  // 128 batch chunks

// ws layout: [0, E*C) floats conf_sum ; then [C] ints counts
// Hot kernel: per-(exit, batch-chunk) block; 250/256 threads each own one
// float4 column-quad, accumulate 64 rows sequentially (coalesced: consecutive
// threads read consecutive 16B), then 4 atomicAdds into the global column sums.
__global__ __launch_bounds__(256) void colsum_kernel(
        const float* __restrict__ logits, float* __restrict__ conf_sum) {
    const int e  = blockIdx.x / NCHUNK_;
    const int bc = blockIdx.x % NCHUNK_;
    const int t  = threadIdx.x;
    if (t >= CQ_) return;
    const float4* base = reinterpret_cast<const float4*>(logits)
                       + (size_t)e * B_ * CQ_ + (size_t)bc * NB_ * CQ_ + t;
    float4 acc = make_float4(0.f, 0.f, 0.f, 0.f);
    #pragma unroll 8
    for (int b = 0; b < NB_; ++b) {
        float4 v = base[(size_t)b * CQ_];
        acc.x += v.x; acc.y += v.y; acc.z += v.z; acc.w += v.w;
    }
    float* o = conf_sum + e * C_ + t * 4;
    atomicAdd(o + 0, acc.x);
    atomicAdd(o + 1, acc.y);
    atomicAdd(o + 2, acc.z);
    atomicAdd(o + 3, acc.w);
}

__global__ void hist_kernel(const int* __restrict__ target,
                            int* __restrict__ counts) {
    const int i = blockIdx.x * blockDim.x + threadIdx.x;
    if (i < B_) atomicAdd(&counts[target[i]], 1);
}

// loss[e] = mean_c |conf_sum[e,c]/B - counts[c]/B|
//         = (1/(B*C)) * sum_c |conf_sum[e,c] - counts[c]|
__global__ void finalize_kernel(const float* __restrict__ conf_sum,
                                const int* __restrict__ counts,
                                float* __restrict__ out) {
    const int e = blockIdx.x;
    const int t = threadIdx.x;
    float s = 0.f;
    for (int c = t; c < C_; c += 256)
        s += fabsf(conf_sum[e * C_ + c] - (float)counts[c]);
    // wave64 butterfly
    #pragma unroll
    for (int off = 32; off > 0; off >>= 1) s += __shfl_down(s, off);
    __shared__ float red[4];
    if ((t & 63) == 0) red[t >> 6] = s;
    __syncthreads();
    if (t == 0) {
        float tot = red[0] + red[1] + red[2] + red[3];
        out[e] = tot / ((float)B_ * (float)C_);
    }
}

extern "C" void kernel_launch(void* const* d_in, const int* in_sizes, int n_in,
                              void* d_out, int out_size, void* d_ws, size_t ws_size,
                              hipStream_t stream) {
    const float* logits = (const float*)d_in[0];
    const int*   target = (const int*)d_in[1];
    float* out      = (float*)d_out;
    float* conf_sum = (float*)d_ws;
    int*   counts   = (int*)((char*)d_ws + (size_t)E_ * C_ * sizeof(float));

    // Atomics accumulate into ws -> must zero it every call (deterministic).
    hipMemsetAsync(d_ws, 0, (size_t)E_ * C_ * sizeof(float) + C_ * sizeof(int),
                   stream);

    hipLaunchKernelGGL(hist_kernel, dim3(B_ / 256), dim3(256), 0, stream,
                       target, counts);
    hipLaunchKernelGGL(colsum_kernel, dim3(E_ * NCHUNK_), dim3(256), 0, stream,
                       logits, conf_sum);
    hipLaunchKernelGGL(finalize_kernel, dim3(E_), dim3(256), 0, stream,
                       conf_sum, counts, out);
}

// Round 2
// 33.723 us; speedup vs baseline: 1.5034x; 1.5034x over previous
//
#include <hip/hip_runtime.h>

// Problem shape (fixed by reference):
//   logits: [E=4, B=8192, C=1000] f32   (131 MB -> memory-bound, floor ~18-21us)
//   target: [B] int32
//   out:    [E] f32
constexpr int E_  = 4;
constexpr int B_  = 8192;
constexpr int C_  = 1000;
constexpr int CQ_ = C_ / 4;          // 250 float4 column-quads
constexpr int NB_ = 64;              // batch rows per block
constexpr int NCHUNK_ = B_ / NB_;    // 128 batch chunks per exit
constexpr int NPART_  = E_ * NCHUNK_; // 512 partial rows
constexpr size_t PARTIAL_BYTES = (size_t)NPART_ * C_ * sizeof(float); // 2,048,000

// ======================= preferred path (2 dispatches) =======================
// Each block owns (exit, 64-row chunk) = 256 KB contiguous; 250/256 threads
// each own one float4 column-quad, accumulate 64 rows (coalesced: a wave reads
// 1 KB/instr), then store the partial NON-atomically. No memset, no atomics.
__global__ __launch_bounds__(256) void colsum_partial(
        const float* __restrict__ logits, float* __restrict__ partial) {
    const int blk = blockIdx.x;          // = e*NCHUNK_ + bc (layout collapses)
    const int t   = threadIdx.x;
    if (t >= CQ_) return;
    const float4* base = reinterpret_cast<const float4*>(logits)
                       + (size_t)blk * NB_ * CQ_ + t;
    float4 acc = make_float4(0.f, 0.f, 0.f, 0.f);
    #pragma unroll 8
    for (int b = 0; b < NB_; ++b) {
        float4 v = base[(size_t)b * CQ_];
        acc.x += v.x; acc.y += v.y; acc.z += v.z; acc.w += v.w;
    }
    reinterpret_cast<float4*>(partial)[(size_t)blk * CQ_ + t] = acc;
}

// 4 blocks (one per exit) x 1024 threads. Each block: LDS histogram of the
// 8192 targets (redundant across blocks, ~32KB read, trivial), then reduce
// 128 partials per column, |sum - count|, block-reduce, write out[e].
__global__ __launch_bounds__(1024) void finalize_partial(
        const float* __restrict__ partial, const int* __restrict__ target,
        float* __restrict__ out) {
    const int e = blockIdx.x;
    const int t = threadIdx.x;
    __shared__ int lh[C_];
    for (int i = t; i < C_; i += 1024) lh[i] = 0;
    __syncthreads();
    for (int i = t; i < B_; i += 1024) atomicAdd(&lh[target[i]], 1);
    __syncthreads();
    float s = 0.f;
    if (t < C_) {
        float sum = 0.f;
        const float* p = partial + (size_t)e * NCHUNK_ * C_ + t;
        #pragma unroll 8
        for (int k = 0; k < NCHUNK_; ++k) sum += p[(size_t)k * C_];
        s = fabsf(sum - (float)lh[t]);
    }
    #pragma unroll
    for (int off = 32; off > 0; off >>= 1) s += __shfl_down(s, off);
    __shared__ float red[16];
    if ((t & 63) == 0) red[t >> 6] = s;
    __syncthreads();
    if (t == 0) {
        float tot = 0.f;
        #pragma unroll
        for (int w = 0; w < 16; ++w) tot += red[w];
        out[e] = tot / ((float)B_ * (float)C_);
    }
}

// ================== fallback path if ws < 2MB (3 dispatches) =================
__global__ __launch_bounds__(1024) void inithist_kernel(
        const int* __restrict__ target, float* __restrict__ conf_sum,
        int* __restrict__ counts) {
    const int t = threadIdx.x;
    __shared__ int lh[C_];
    for (int i = t; i < C_; i += 1024) lh[i] = 0;
    for (int i = t; i < E_ * C_; i += 1024) conf_sum[i] = 0.f;
    __syncthreads();
    for (int i = t; i < B_; i += 1024) atomicAdd(&lh[target[i]], 1);
    __syncthreads();
    for (int i = t; i < C_; i += 1024) counts[i] = lh[i];
}

__global__ __launch_bounds__(256) void colsum_atomic(
        const float* __restrict__ logits, float* __restrict__ conf_sum) {
    const int e  = blockIdx.x / NCHUNK_;
    const int t  = threadIdx.x;
    if (t >= CQ_) return;
    const float4* base = reinterpret_cast<const float4*>(logits)
                       + (size_t)blockIdx.x * NB_ * CQ_ + t;
    float4 acc = make_float4(0.f, 0.f, 0.f, 0.f);
    #pragma unroll 8
    for (int b = 0; b < NB_; ++b) {
        float4 v = base[(size_t)b * CQ_];
        acc.x += v.x; acc.y += v.y; acc.z += v.z; acc.w += v.w;
    }
    float* o = conf_sum + e * C_ + t * 4;
    atomicAdd(o + 0, acc.x);
    atomicAdd(o + 1, acc.y);
    atomicAdd(o + 2, acc.z);
    atomicAdd(o + 3, acc.w);
}

__global__ __launch_bounds__(256) void finalize_atomic(
        const float* __restrict__ conf_sum, const int* __restrict__ counts,
        float* __restrict__ out) {
    const int e = blockIdx.x;
    const int t = threadIdx.x;
    float s = 0.f;
    for (int c = t; c < C_; c += 256)
        s += fabsf(conf_sum[e * C_ + c] - (float)counts[c]);
    #pragma unroll
    for (int off = 32; off > 0; off >>= 1) s += __shfl_down(s, off);
    __shared__ float red[4];
    if ((t & 63) == 0) red[t >> 6] = s;
    __syncthreads();
    if (t == 0) out[e] = (red[0] + red[1] + red[2] + red[3])
                         / ((float)B_ * (float)C_);
}

extern "C" void kernel_launch(void* const* d_in, const int* in_sizes, int n_in,
                              void* d_out, int out_size, void* d_ws, size_t ws_size,
                              hipStream_t stream) {
    const float* logits = (const float*)d_in[0];
    const int*   target = (const int*)d_in[1];
    float* out = (float*)d_out;

    if (ws_size >= PARTIAL_BYTES) {
        float* partial = (float*)d_ws;
        hipLaunchKernelGGL(colsum_partial, dim3(NPART_), dim3(256), 0, stream,
                           logits, partial);
        hipLaunchKernelGGL(finalize_partial, dim3(E_), dim3(1024), 0, stream,
                           partial, target, out);
    } else {
        float* conf_sum = (float*)d_ws;
        int*   counts   = (int*)((char*)d_ws + (size_t)E_ * C_ * sizeof(float));
        hipLaunchKernelGGL(inithist_kernel, dim3(1), dim3(1024), 0, stream,
                           target, conf_sum, counts);
        hipLaunchKernelGGL(colsum_atomic, dim3(NPART_), dim3(256), 0, stream,
                           logits, conf_sum);
        hipLaunchKernelGGL(finalize_atomic, dim3(E_), dim3(256), 0, stream,
                           conf_sum, counts, out);
    }
}